// Round 1
// 466.767 us; speedup vs baseline: 1.0424x; 1.0424x over previous
//
#include <hip/hip_runtime.h>
#include <stdint.h>

// VQVAE quantise, fp32 in/out.
// R1: (a) double-buffered LDS + software-pipelined staging in argmin_mfma
//     (prefetch next 128-row dict tile into regs before MFMA phase, convert
//     into the other LDS buffer after; one barrier/iter). LDS 143.6 KB —
//     fine since grid=256 means 1 block/CU anyway.
//     (b) replace hipMemsetAsync(268MB) + scatter_ones with a fused
//     vectorized zero+one writer (one pass, float4 nontemporal stores).
// Math order (split8 / MFMA sequence / dsq accumulation / tie-break) is
// bit-identical to the 485µs baseline that passed with absmax 0.
// ws: idx int32 [256*64].

#define B_SZ 256
#define C_SZ 64
#define E_SZ 128
#define S_SZ 4096
#define CW   8192
#define LDB  136   // LDS B-row stride in f16

typedef __attribute__((ext_vector_type(4))) float    float4a;
typedef __attribute__((ext_vector_type(8))) _Float16 half8;

__device__ __forceinline__ void split8(float4a f0, float4a f1, half8& hi, half8& lo) {
    #pragma unroll
    for (int j = 0; j < 4; ++j) {
        _Float16 h0 = (_Float16)f0[j];
        hi[j]     = h0;
        lo[j]     = (_Float16)(f0[j] - (float)h0);
        _Float16 h1 = (_Float16)f1[j];
        hi[4 + j] = h1;
        lo[4 + j] = (_Float16)(f1[j] - (float)h1);
    }
}

// grid 256 = (btile 0..3) x (c 0..63), block 512 = 8 waves (mhalf x nquad).
__global__ __launch_bounds__(512, 2) void argmin_mfma(
    const float* __restrict__ x,
    const float* __restrict__ dict,
    int* __restrict__ idx_out,
    float* __restrict__ cw_out)
{
    __shared__ __attribute__((aligned(16))) _Float16 bh[2][128 * LDB];  // 2x34.8 KB
    __shared__ __attribute__((aligned(16))) _Float16 bl[2][128 * LDB];  // 2x34.8 KB
    __shared__ float4a dsqp[2][128];
    __shared__ int     fid[64];
    // final reduction tables aliased onto staging LDS (used after the loop)
    float* rv = reinterpret_cast<float*>(bh);   // 64*64 floats = 16 KB
    int*   ri = reinterpret_cast<int*>(bl);     // 64*64 ints   = 16 KB

    const int tid   = threadIdx.x;
    const int lane  = tid & 63;
    const int quad  = lane >> 4;
    const int l15   = lane & 15;
    const int wid   = tid >> 6;
    const int mhalf = wid & 1;
    const int nquad = wid >> 1;
    const int c     = blockIdx.x & 63;
    const int btile = blockIdx.x >> 6;

    // ---- runtime layout probes: true (row, col) of each (lane, reg) ----
    int m_attr[4], n_attr[4];
    {
        half8 ones, enc;
        #pragma unroll
        for (int j = 0; j < 8; ++j) { ones[j] = (_Float16)1.0f; enc[j] = (_Float16)(float)l15; }
        float4a z = {0.f, 0.f, 0.f, 0.f};
        float4a pr = __builtin_amdgcn_mfma_f32_16x16x32_f16(enc, ones, z, 0, 0, 0);
        float4a pc = __builtin_amdgcn_mfma_f32_16x16x32_f16(ones, enc, z, 0, 0, 0);
        #pragma unroll
        for (int r = 0; r < 4; ++r) {
            m_attr[r] = (int)(pr[r] * 0.03125f + 0.5f);   // row feeding this element
            n_attr[r] = (int)(pc[r] * 0.03125f + 0.5f);   // col feeding this element
        }
    }

    // ---- A fragments (regs, whole kernel): loader believes A[m=l15][k=kk*32+quad*8+j] ----
    half8 ah[2][4], al[2][4];
    #pragma unroll
    for (int mi = 0; mi < 2; ++mi) {
        int b = btile * 64 + mhalf * 32 + mi * 16 + l15;
        const float* xr = x + (size_t)b * CW + c * E_SZ;
        #pragma unroll
        for (int kk = 0; kk < 4; ++kk) {
            float4a f0 = *reinterpret_cast<const float4a*>(xr + kk * 32 + quad * 8);
            float4a f1 = *reinterpret_cast<const float4a*>(xr + kk * 32 + quad * 8 + 4);
            split8(f0, f1, ah[mi][kk], al[mi][kk]);
        }
    }

    // ---- staging coords (fixed per thread) ----
    const int srow = tid >> 2;
    const int kq   = (tid & 3) * 32;
    const int q4   = tid & 3;
    const float* drow = dict + ((size_t)c * S_SZ + srow) * E_SZ + kq;

    // ---- prologue: issue + convert tile 0 into buffer 0 ----
    float4a pf0[4], pf1[4];
    #pragma unroll
    for (int ck = 0; ck < 4; ++ck) {
        pf0[ck] = *reinterpret_cast<const float4a*>(drow + ck * 8);
        pf1[ck] = *reinterpret_cast<const float4a*>(drow + ck * 8 + 4);
    }
    {
        float dp = 0.f;
        #pragma unroll
        for (int ck = 0; ck < 4; ++ck) {
            half8 h, l;
            split8(pf0[ck], pf1[ck], h, l);
            #pragma unroll
            for (int j = 0; j < 4; ++j) {
                dp = fmaf(pf0[ck][j], pf0[ck][j], dp);
                dp = fmaf(pf1[ck][j], pf1[ck][j], dp);
            }
            *reinterpret_cast<half8*>(&bh[0][srow * LDB + kq + ck * 8]) = h;
            *reinterpret_cast<half8*>(&bl[0][srow * LDB + kq + ck * 8]) = l;
        }
        dsqp[0][srow][q4] = dp;
    }

    float bestv[8];
    int   besti[8];
    #pragma unroll
    for (int i = 0; i < 8; ++i) { bestv[i] = 3.4e38f; besti[i] = 0; }

    __syncthreads();

    int cur = 0;
    for (int it = 0; it < 32; ++it) {
        const int s0 = it * 128;

        // ---- issue next tile's global loads (latency hides under MFMA) ----
        if (it + 1 < 32) {
            const float* dr = drow + (size_t)(it + 1) * (128 * E_SZ);
            #pragma unroll
            for (int ck = 0; ck < 4; ++ck) {
                pf0[ck] = *reinterpret_cast<const float4a*>(dr + ck * 8);
                pf1[ck] = *reinterpret_cast<const float4a*>(dr + ck * 8 + 4);
            }
        }

        // ---- MFMA phase on buf[cur] ----
        const _Float16* bhc = bh[cur];
        const _Float16* blc = bl[cur];
        float4a acc[2][2] = {{{0.f,0.f,0.f,0.f},{0.f,0.f,0.f,0.f}},
                             {{0.f,0.f,0.f,0.f},{0.f,0.f,0.f,0.f}}};
        #pragma unroll
        for (int kk = 0; kk < 4; ++kk) {
            half8 bhf[2], blf[2];
            #pragma unroll
            for (int ni = 0; ni < 2; ++ni) {
                const int sl = nquad * 32 + ni * 16 + l15;   // loader believes col = l15
                bhf[ni] = *reinterpret_cast<const half8*>(bhc + sl * LDB + kk * 32 + quad * 8);
                blf[ni] = *reinterpret_cast<const half8*>(blc + sl * LDB + kk * 32 + quad * 8);
            }
            #pragma unroll
            for (int mi = 0; mi < 2; ++mi)
                #pragma unroll
                for (int ni = 0; ni < 2; ++ni) {
                    acc[mi][ni] = __builtin_amdgcn_mfma_f32_16x16x32_f16(
                        ah[mi][kk], bhf[ni], acc[mi][ni], 0, 0, 0);
                    acc[mi][ni] = __builtin_amdgcn_mfma_f32_16x16x32_f16(
                        ah[mi][kk], blf[ni], acc[mi][ni], 0, 0, 0);
                    acc[mi][ni] = __builtin_amdgcn_mfma_f32_16x16x32_f16(
                        al[mi][kk], bhf[ni], acc[mi][ni], 0, 0, 0);
                }
        }

        // ---- epilogue: dist = d_sq - 2*cross (x_sq const per (b,c): argmin-invariant) ----
        #pragma unroll
        for (int ni = 0; ni < 2; ++ni)
            #pragma unroll
            for (int r = 0; r < 4; ++r) {
                const int sl = nquad * 32 + ni * 16 + n_attr[r];   // true col attribution
                float4a q4v = dsqp[cur][sl];
                float dsq = (q4v[0] + q4v[1]) + (q4v[2] + q4v[3]);
                int sg = s0 + sl;
                #pragma unroll
                for (int mi = 0; mi < 2; ++mi) {
                    float dist = dsq - 2.0f * acc[mi][ni][r];
                    int slot = mi * 4 + r;
                    if (dist < bestv[slot]) { bestv[slot] = dist; besti[slot] = sg; }
                }
            }

        // ---- convert prefetched tile into buf[cur^1] ----
        if (it + 1 < 32) {
            const int nb = cur ^ 1;
            float dp = 0.f;
            #pragma unroll
            for (int ck = 0; ck < 4; ++ck) {
                half8 h, l;
                split8(pf0[ck], pf1[ck], h, l);
                #pragma unroll
                for (int j = 0; j < 4; ++j) {
                    dp = fmaf(pf0[ck][j], pf0[ck][j], dp);
                    dp = fmaf(pf1[ck][j], pf1[ck][j], dp);
                }
                *reinterpret_cast<half8*>(&bh[nb][srow * LDB + kq + ck * 8]) = h;
                *reinterpret_cast<half8*>(&bl[nb][srow * LDB + kq + ck * 8]) = l;
            }
            dsqp[nb][srow][q4] = dp;
        }
        __syncthreads();
        cur ^= 1;
    }

    // loop-end barrier guarantees all LDS reads done; safe to alias rv/ri

    // ---- dump: bijective 64x64 scatter using true (row,col) attribution ----
    #pragma unroll
    for (int mi = 0; mi < 2; ++mi)
        #pragma unroll
        for (int r = 0; r < 4; ++r) {
            int row = mhalf * 32 + mi * 16 + m_attr[r];
            int col = nquad * 16 + n_attr[r];
            rv[row * 64 + col] = bestv[mi * 4 + r];
            ri[row * 64 + col] = besti[mi * 4 + r];
        }
    __syncthreads();

    if (tid < 64) {
        float bv = 3.4e38f; int bi = 0x7fffffff;
        for (int j = 0; j < 64; ++j) {
            float v = rv[tid * 64 + j];
            int   i = ri[tid * 64 + j];
            if (v < bv || (v == bv && i < bi)) { bv = v; bi = i; }  // first-occurrence tie
        }
        idx_out[(btile * 64 + tid) * C_SZ + c] = bi;
        fid[tid] = bi;
    }
    __syncthreads();

    // ---- gather cw_embed: 64 rows x 32 float4 chunks ----
    for (int u = tid; u < 64 * 32; u += 512) {
        int row = u >> 5, ch = u & 31;
        int bi = fid[row];
        float4a v = *reinterpret_cast<const float4a*>(
            dict + ((size_t)c * S_SZ + bi) * E_SZ + ch * 4);
        *reinterpret_cast<float4a*>(
            cw_out + (size_t)(btile * 64 + row) * CW + c * E_SZ + ch * 4) = v;
    }
}

// Fused one-hot writer: zeros + the single 1.0 per row, one streaming pass.
// grid = B*C rows, 256 threads; each thread stores 4x float4 (16 KB/row).
__global__ __launch_bounds__(256) void fill_onehot(
    const int* __restrict__ idx, float* __restrict__ oh)
{
    const int row = blockIdx.x;
    const int bi  = idx[row];
    float* base = oh + (size_t)row * S_SZ;
    const int t = threadIdx.x;
    #pragma unroll
    for (int j = 0; j < 4; ++j) {
        const int ch = j * 256 + t;
        float4a v = {0.f, 0.f, 0.f, 0.f};
        if ((bi >> 2) == ch) v[bi & 3] = 1.0f;
        __builtin_nontemporal_store(v, reinterpret_cast<float4a*>(base + (size_t)ch * 4));
    }
}

extern "C" void kernel_launch(void* const* d_in, const int* in_sizes, int n_in,
                              void* d_out, int out_size, void* d_ws, size_t ws_size,
                              hipStream_t stream) {
    const float* x    = (const float*)d_in[0];
    const float* dict = (const float*)d_in[1];
    float* out = (float*)d_out;
    int* idx = (int*)d_ws;
    float* oh = out + (size_t)B_SZ * CW;

    argmin_mfma<<<dim3(256), dim3(512), 0, stream>>>(x, dict, idx, out);
    fill_onehot<<<dim3(B_SZ * C_SZ), dim3(256), 0, stream>>>(idx, oh);
}

// Round 2
// 462.495 us; speedup vs baseline: 1.0521x; 1.0092x over previous
//
#include <hip/hip_runtime.h>
#include <stdint.h>

// VQVAE quantise, fp32 in/out.
// R2: single fused kernel. The separate fill_onehot (a 2nd full 268 MB
// streaming pass) is folded into argmin_mfma: each block zeroes its own
// 64 one-hot rows with nontemporal stores spread across the 32 main-loop
// iterations (rides on idle HBM BW under MFMA/convert; drains at the
// per-iter barrier's vmcnt(0)), then writes its 64 ones after the final
// reduction. idx/ws round-trip removed. s_setprio(1) around MFMA cluster.
// Distance math (split8 / MFMA sequence / dsq accumulation / tie-break)
// bit-identical to the passing baseline (absmax 0).

#define B_SZ 256
#define C_SZ 64
#define E_SZ 128
#define S_SZ 4096
#define CW   8192
#define LDB  136   // LDS B-row stride in f16

typedef __attribute__((ext_vector_type(4))) float    float4a;
typedef __attribute__((ext_vector_type(8))) _Float16 half8;

__device__ __forceinline__ void split8(float4a f0, float4a f1, half8& hi, half8& lo) {
    #pragma unroll
    for (int j = 0; j < 4; ++j) {
        _Float16 h0 = (_Float16)f0[j];
        hi[j]     = h0;
        lo[j]     = (_Float16)(f0[j] - (float)h0);
        _Float16 h1 = (_Float16)f1[j];
        hi[4 + j] = h1;
        lo[4 + j] = (_Float16)(f1[j] - (float)h1);
    }
}

// grid 256 = (btile 0..3) x (c 0..63), block 512 = 8 waves (mhalf x nquad).
__global__ __launch_bounds__(512, 2) void argmin_mfma(
    const float* __restrict__ x,
    const float* __restrict__ dict,
    float* __restrict__ cw_out,
    float* __restrict__ oh)
{
    __shared__ __attribute__((aligned(16))) _Float16 bh[2][128 * LDB];  // 2x34.8 KB
    __shared__ __attribute__((aligned(16))) _Float16 bl[2][128 * LDB];  // 2x34.8 KB
    __shared__ float4a dsqp[2][128];
    __shared__ int     fid[64];
    // final reduction tables aliased onto staging LDS (used after the loop)
    float* rv = reinterpret_cast<float*>(bh);   // 64*64 floats = 16 KB
    int*   ri = reinterpret_cast<int*>(bl);     // 64*64 ints   = 16 KB

    const int tid   = threadIdx.x;
    const int lane  = tid & 63;
    const int quad  = lane >> 4;
    const int l15   = lane & 15;
    const int wid   = tid >> 6;
    const int mhalf = wid & 1;
    const int nquad = wid >> 1;
    const int c     = blockIdx.x & 63;
    const int btile = blockIdx.x >> 6;

    // ---- runtime layout probes: true (row, col) of each (lane, reg) ----
    int m_attr[4], n_attr[4];
    {
        half8 ones, enc;
        #pragma unroll
        for (int j = 0; j < 8; ++j) { ones[j] = (_Float16)1.0f; enc[j] = (_Float16)(float)l15; }
        float4a z = {0.f, 0.f, 0.f, 0.f};
        float4a pr = __builtin_amdgcn_mfma_f32_16x16x32_f16(enc, ones, z, 0, 0, 0);
        float4a pc = __builtin_amdgcn_mfma_f32_16x16x32_f16(ones, enc, z, 0, 0, 0);
        #pragma unroll
        for (int r = 0; r < 4; ++r) {
            m_attr[r] = (int)(pr[r] * 0.03125f + 0.5f);   // row feeding this element
            n_attr[r] = (int)(pc[r] * 0.03125f + 0.5f);   // col feeding this element
        }
    }

    // ---- A fragments (regs, whole kernel): loader believes A[m=l15][k=kk*32+quad*8+j] ----
    half8 ah[2][4], al[2][4];
    #pragma unroll
    for (int mi = 0; mi < 2; ++mi) {
        int b = btile * 64 + mhalf * 32 + mi * 16 + l15;
        const float* xr = x + (size_t)b * CW + c * E_SZ;
        #pragma unroll
        for (int kk = 0; kk < 4; ++kk) {
            float4a f0 = *reinterpret_cast<const float4a*>(xr + kk * 32 + quad * 8);
            float4a f1 = *reinterpret_cast<const float4a*>(xr + kk * 32 + quad * 8 + 4);
            split8(f0, f1, ah[mi][kk], al[mi][kk]);
        }
    }

    // ---- staging coords (fixed per thread) ----
    const int srow = tid >> 2;
    const int kq   = (tid & 3) * 32;
    const int q4   = tid & 3;
    const float* drow = dict + ((size_t)c * S_SZ + srow) * E_SZ + kq;

    // ---- one-hot base for this block: rows (btile*64 + r)*C + c ----
    float* ohb = oh + ((size_t)(btile * 64) * C_SZ + c) * S_SZ;
    const size_t oh_bstride = (size_t)C_SZ * S_SZ;   // stride between consecutive b

    // ---- prologue: issue + convert tile 0 into buffer 0 ----
    float4a pf0[4], pf1[4];
    #pragma unroll
    for (int ck = 0; ck < 4; ++ck) {
        pf0[ck] = *reinterpret_cast<const float4a*>(drow + ck * 8);
        pf1[ck] = *reinterpret_cast<const float4a*>(drow + ck * 8 + 4);
    }
    {
        float dp = 0.f;
        #pragma unroll
        for (int ck = 0; ck < 4; ++ck) {
            half8 h, l;
            split8(pf0[ck], pf1[ck], h, l);
            #pragma unroll
            for (int j = 0; j < 4; ++j) {
                dp = fmaf(pf0[ck][j], pf0[ck][j], dp);
                dp = fmaf(pf1[ck][j], pf1[ck][j], dp);
            }
            *reinterpret_cast<half8*>(&bh[0][srow * LDB + kq + ck * 8]) = h;
            *reinterpret_cast<half8*>(&bl[0][srow * LDB + kq + ck * 8]) = l;
        }
        dsqp[0][srow][q4] = dp;
    }

    float bestv[8];
    int   besti[8];
    #pragma unroll
    for (int i = 0; i < 8; ++i) { bestv[i] = 3.4e38f; besti[i] = 0; }

    __syncthreads();

    int cur = 0;
    for (int it = 0; it < 32; ++it) {
        const int s0 = it * 128;

        // ---- issue next tile's global loads (latency hides under MFMA) ----
        if (it + 1 < 32) {
            const float* dr = drow + (size_t)(it + 1) * (128 * E_SZ);
            #pragma unroll
            for (int ck = 0; ck < 4; ++ck) {
                pf0[ck] = *reinterpret_cast<const float4a*>(dr + ck * 8);
                pf1[ck] = *reinterpret_cast<const float4a*>(dr + ck * 8 + 4);
            }
        }

        // ---- zero 2 of this block's 64 one-hot rows (nt stores; they have
        //      the whole MFMA+convert phase to drain before the barrier) ----
        {
            float4a zz = {0.f, 0.f, 0.f, 0.f};
            float* z0 = ohb + (size_t)(it * 2) * oh_bstride;
            float* z1 = z0 + oh_bstride;
            __builtin_nontemporal_store(zz, reinterpret_cast<float4a*>(z0) + tid);
            __builtin_nontemporal_store(zz, reinterpret_cast<float4a*>(z0) + 512 + tid);
            __builtin_nontemporal_store(zz, reinterpret_cast<float4a*>(z1) + tid);
            __builtin_nontemporal_store(zz, reinterpret_cast<float4a*>(z1) + 512 + tid);
        }

        // ---- MFMA phase on buf[cur] ----
        const _Float16* bhc = bh[cur];
        const _Float16* blc = bl[cur];
        float4a acc[2][2] = {{{0.f,0.f,0.f,0.f},{0.f,0.f,0.f,0.f}},
                             {{0.f,0.f,0.f,0.f},{0.f,0.f,0.f,0.f}}};
        __builtin_amdgcn_s_setprio(1);
        #pragma unroll
        for (int kk = 0; kk < 4; ++kk) {
            half8 bhf[2], blf[2];
            #pragma unroll
            for (int ni = 0; ni < 2; ++ni) {
                const int sl = nquad * 32 + ni * 16 + l15;   // loader believes col = l15
                bhf[ni] = *reinterpret_cast<const half8*>(bhc + sl * LDB + kk * 32 + quad * 8);
                blf[ni] = *reinterpret_cast<const half8*>(blc + sl * LDB + kk * 32 + quad * 8);
            }
            #pragma unroll
            for (int mi = 0; mi < 2; ++mi)
                #pragma unroll
                for (int ni = 0; ni < 2; ++ni) {
                    acc[mi][ni] = __builtin_amdgcn_mfma_f32_16x16x32_f16(
                        ah[mi][kk], bhf[ni], acc[mi][ni], 0, 0, 0);
                    acc[mi][ni] = __builtin_amdgcn_mfma_f32_16x16x32_f16(
                        ah[mi][kk], blf[ni], acc[mi][ni], 0, 0, 0);
                    acc[mi][ni] = __builtin_amdgcn_mfma_f32_16x16x32_f16(
                        al[mi][kk], bhf[ni], acc[mi][ni], 0, 0, 0);
                }
        }
        __builtin_amdgcn_s_setprio(0);

        // ---- epilogue: dist = d_sq - 2*cross (x_sq const per (b,c): argmin-invariant) ----
        #pragma unroll
        for (int ni = 0; ni < 2; ++ni)
            #pragma unroll
            for (int r = 0; r < 4; ++r) {
                const int sl = nquad * 32 + ni * 16 + n_attr[r];   // true col attribution
                float4a q4v = dsqp[cur][sl];
                float dsq = (q4v[0] + q4v[1]) + (q4v[2] + q4v[3]);
                int sg = s0 + sl;
                #pragma unroll
                for (int mi = 0; mi < 2; ++mi) {
                    float dist = dsq - 2.0f * acc[mi][ni][r];
                    int slot = mi * 4 + r;
                    if (dist < bestv[slot]) { bestv[slot] = dist; besti[slot] = sg; }
                }
            }

        // ---- convert prefetched tile into buf[cur^1] ----
        if (it + 1 < 32) {
            const int nb = cur ^ 1;
            float dp = 0.f;
            #pragma unroll
            for (int ck = 0; ck < 4; ++ck) {
                half8 h, l;
                split8(pf0[ck], pf1[ck], h, l);
                #pragma unroll
                for (int j = 0; j < 4; ++j) {
                    dp = fmaf(pf0[ck][j], pf0[ck][j], dp);
                    dp = fmaf(pf1[ck][j], pf1[ck][j], dp);
                }
                *reinterpret_cast<half8*>(&bh[nb][srow * LDB + kq + ck * 8]) = h;
                *reinterpret_cast<half8*>(&bl[nb][srow * LDB + kq + ck * 8]) = l;
            }
            dsqp[nb][srow][q4] = dp;
        }
        __syncthreads();   // drains vmcnt(0): zero-stores + prefetch complete
        cur ^= 1;
    }

    // loop-end barrier guarantees all LDS reads done; safe to alias rv/ri.
    // All 64 one-hot rows of this block are zeroed (drained at iter barriers).

    // ---- dump: bijective 64x64 scatter using true (row,col) attribution ----
    #pragma unroll
    for (int mi = 0; mi < 2; ++mi)
        #pragma unroll
        for (int r = 0; r < 4; ++r) {
            int row = mhalf * 32 + mi * 16 + m_attr[r];
            int col = nquad * 16 + n_attr[r];
            rv[row * 64 + col] = bestv[mi * 4 + r];
            ri[row * 64 + col] = besti[mi * 4 + r];
        }
    __syncthreads();

    if (tid < 64) {
        float bv = 3.4e38f; int bi = 0x7fffffff;
        for (int j = 0; j < 64; ++j) {
            float v = rv[tid * 64 + j];
            int   i = ri[tid * 64 + j];
            if (v < bv || (v == bv && i < bi)) { bv = v; bi = i; }  // first-occurrence tie
        }
        fid[tid] = bi;
        // write the single 1.0 for row (btile*64+tid, c); zero-stores to this
        // line completed at the last loop barrier (vmcnt(0) per wave + join)
        ohb[(size_t)tid * oh_bstride + bi] = 1.0f;
    }
    __syncthreads();

    // ---- gather cw_embed: 64 rows x 32 float4 chunks ----
    for (int u = tid; u < 64 * 32; u += 512) {
        int row = u >> 5, ch = u & 31;
        int bi = fid[row];
        float4a v = *reinterpret_cast<const float4a*>(
            dict + ((size_t)c * S_SZ + bi) * E_SZ + ch * 4);
        *reinterpret_cast<float4a*>(
            cw_out + (size_t)(btile * 64 + row) * CW + c * E_SZ + ch * 4) = v;
    }
}

extern "C" void kernel_launch(void* const* d_in, const int* in_sizes, int n_in,
                              void* d_out, int out_size, void* d_ws, size_t ws_size,
                              hipStream_t stream) {
    const float* x    = (const float*)d_in[0];
    const float* dict = (const float*)d_in[1];
    float* out = (float*)d_out;
    float* oh  = out + (size_t)B_SZ * CW;

    argmin_mfma<<<dim3(256), dim3(512), 0, stream>>>(x, dict, out, oh);
}